// Round 1
// baseline (2221.788 us; speedup 1.0000x reference)
//
#include <hip/hip_runtime.h>
#include <math.h>

#define HID 64
#define ANNOT 512
#define NSTEPS 8

__device__ __forceinline__ float sigmoidf_(float x) { return 1.0f / (1.0f + __expf(-x)); }

__device__ __forceinline__ unsigned enc_f(float f) {
  unsigned u = __float_as_uint(f);
  return (f < 0.f) ? ~u : (u | 0x80000000u);
}
__device__ __forceinline__ float dec_f(unsigned u) {
  return (u & 0x80000000u) ? __uint_as_float(u & 0x7FFFFFFFu) : __uint_as_float(~u);
}

// ---------------- reduce GEMM: h[n,64] = x[n,512] @ Wr[512,64] + br ----------------
__global__ __launch_bounds__(256) void k_reduce(
    const float* __restrict__ x, const float* __restrict__ Wr,
    const float* __restrict__ br, float* __restrict__ h, int n_nodes)
{
  __shared__ float As[32][64];  // As[k][m] (x tile transposed)
  __shared__ float Bs[32][64];  // Bs[k][n]
  const int tid = threadIdx.x;
  const int tx = tid & 15, ty = tid >> 4;
  const int bm = blockIdx.x * 64;
  float acc[4][4] = {};
  const int mA = tid >> 2;
  const int kA = (tid & 3) * 8;
  const int kB = tid >> 3;
  const int nB = (tid & 7) * 8;
  const bool mvalid = (bm + mA) < n_nodes;
  const size_t rowA = (size_t)(bm + mA) * ANNOT;

  for (int kt = 0; kt < ANNOT; kt += 32) {
    float4 a0 = make_float4(0, 0, 0, 0), a1 = a0;
    if (mvalid) {
      a0 = *(const float4*)(x + rowA + kt + kA);
      a1 = *(const float4*)(x + rowA + kt + kA + 4);
    }
    float4 b0 = *(const float4*)(Wr + (size_t)(kt + kB) * HID + nB);
    float4 b1 = *(const float4*)(Wr + (size_t)(kt + kB) * HID + nB + 4);
    __syncthreads();
    As[kA + 0][mA] = a0.x; As[kA + 1][mA] = a0.y; As[kA + 2][mA] = a0.z; As[kA + 3][mA] = a0.w;
    As[kA + 4][mA] = a1.x; As[kA + 5][mA] = a1.y; As[kA + 6][mA] = a1.z; As[kA + 7][mA] = a1.w;
    *(float4*)&Bs[kB][nB] = b0;
    *(float4*)&Bs[kB][nB + 4] = b1;
    __syncthreads();
#pragma unroll
    for (int k = 0; k < 32; ++k) {
      float4 av = *(const float4*)&As[k][ty * 4];
      float4 bv = *(const float4*)&Bs[k][tx * 4];
      acc[0][0] += av.x * bv.x; acc[0][1] += av.x * bv.y; acc[0][2] += av.x * bv.z; acc[0][3] += av.x * bv.w;
      acc[1][0] += av.y * bv.x; acc[1][1] += av.y * bv.y; acc[1][2] += av.y * bv.z; acc[1][3] += av.y * bv.w;
      acc[2][0] += av.z * bv.x; acc[2][1] += av.z * bv.y; acc[2][2] += av.z * bv.z; acc[2][3] += av.z * bv.w;
      acc[3][0] += av.w * bv.x; acc[3][1] += av.w * bv.y; acc[3][2] += av.w * bv.z; acc[3][3] += av.w * bv.w;
    }
  }
  float4 bias = *(const float4*)(br + tx * 4);
#pragma unroll
  for (int i = 0; i < 4; ++i) {
    int row = bm + ty * 4 + i;
    if (row < n_nodes) {
      float4 o;
      o.x = acc[i][0] + bias.x; o.y = acc[i][1] + bias.y;
      o.z = acc[i][2] + bias.z; o.w = acc[i][3] + bias.w;
      *(float4*)(h + (size_t)row * HID + tx * 4) = o;
    }
  }
}

// ------------- Bbig precompute: [8][128][256], col c = f*4+sec (interleaved) -------------
// rows k<64 (aggr part):  sec0: (W_s @ w_ih_r^T)[k][f]; sec1: z; sec2: n; sec3: 0
// rows k>=64 (h part):    sec0: w_hh[f][k2]; sec1: w_hh[64+f][k2]; sec2: 0; sec3: w_hh[128+f][k2]
__global__ void k_bbig(const float* __restrict__ ggc_w, const float* __restrict__ w_ih,
                       const float* __restrict__ w_hh, float* __restrict__ Bbig)
{
  int s = blockIdx.y;
  int k = blockIdx.x;       // 0..127
  int c = threadIdx.x;      // 0..255
  int f = c >> 2, sec = c & 3;
  float v = 0.f;
  if (k < 64) {
    if (sec < 3) {
      const float* Ws = ggc_w + ((size_t)s * 64 + k) * 64;
      const float* wr = w_ih + (size_t)(sec * 64 + f) * 64;
      float a = 0.f;
      for (int j = 0; j < 64; ++j) a += Ws[j] * wr[j];
      v = a;
    }
  } else {
    int k2 = k - 64;
    if (sec == 0)      v = w_hh[(size_t)f * 64 + k2];
    else if (sec == 1) v = w_hh[(size_t)(64 + f) * 64 + k2];
    else if (sec == 3) v = w_hh[(size_t)(128 + f) * 64 + k2];
  }
  Bbig[((size_t)s * 128 + k) * 256 + c] = v;
}

// ---------------- CSR build ----------------
__global__ void k_hist(const int* __restrict__ dstv, int E, int* __restrict__ cnt) {
  int e = blockIdx.x * blockDim.x + threadIdx.x;
  if (e < E) atomicAdd(&cnt[dstv[e]], 1);
}

__global__ __launch_bounds__(1024) void k_scan1(const int* __restrict__ cnt, int n, int* __restrict__ bsum) {
  __shared__ int sd[1024];
  int i = blockIdx.x * 1024 + threadIdx.x;
  sd[threadIdx.x] = (i < n) ? cnt[i] : 0;
  __syncthreads();
  for (int s = 512; s > 0; s >>= 1) {
    if (threadIdx.x < s) sd[threadIdx.x] += sd[threadIdx.x + s];
    __syncthreads();
  }
  if (threadIdx.x == 0) bsum[blockIdx.x] = sd[0];
}

__global__ void k_scan2(const int* __restrict__ bsum, int nb, int* __restrict__ boff,
                        int* __restrict__ row_ptr, int n_nodes) {
  if (threadIdx.x == 0 && blockIdx.x == 0) {
    int run = 0;
    for (int b = 0; b < nb; ++b) { boff[b] = run; run += bsum[b]; }
    row_ptr[n_nodes] = run;
  }
}

__global__ __launch_bounds__(1024) void k_scan3(const int* __restrict__ cnt, int n,
                                                const int* __restrict__ boff,
                                                int* __restrict__ row_ptr, int* __restrict__ cursor) {
  __shared__ int sd[1024];
  int i = blockIdx.x * 1024 + threadIdx.x;
  int v = (i < n) ? cnt[i] : 0;
  sd[threadIdx.x] = v;
  __syncthreads();
  for (int d = 1; d < 1024; d <<= 1) {
    int t = (threadIdx.x >= d) ? sd[threadIdx.x - d] : 0;
    __syncthreads();
    sd[threadIdx.x] += t;
    __syncthreads();
  }
  if (i < n) {
    int excl = boff[blockIdx.x] + sd[threadIdx.x] - v;
    row_ptr[i] = excl;
    cursor[i] = excl;
  }
}

__global__ void k_fill(const int* __restrict__ src, const int* __restrict__ dstv, int E,
                       int* __restrict__ cursor, int* __restrict__ csr_src) {
  int e = blockIdx.x * blockDim.x + threadIdx.x;
  if (e < E) {
    int d = dstv[e];
    int pos = atomicAdd(&cursor[d], 1);
    csr_src[pos] = src[e];
  }
}

// ---------------- per-step: CSR gather-sum of h ----------------
__global__ __launch_bounds__(256) void k_aggr(
    const float* __restrict__ h, const int* __restrict__ row_ptr,
    const int* __restrict__ csr_src, float* __restrict__ aggr, int n_nodes)
{
  int wave = threadIdx.x >> 6;
  int lane = threadIdx.x & 63;
  int n = blockIdx.x * 4 + wave;
  if (n >= n_nodes) return;
  int beg = row_ptr[n], end = row_ptr[n + 1];
  float acc = 0.f;
  for (int e = beg; e < end; ++e) {
    int s = csr_src[e];
    acc += h[(size_t)s * HID + lane];
  }
  aggr[(size_t)n * HID + lane] = acc;
}

// ---------------- per-step: fused dual-GEMM + GRU gates (in-place h update) ----------------
// C[64 rows][256 cols] = [aggr | h] (K=128) @ Bbig_s (128x256), cols interleaved f*4+sec
__global__ __launch_bounds__(512) void k_gru(
    const float* __restrict__ aggr, float* __restrict__ h,
    const float* __restrict__ Bbig_s,
    const float* __restrict__ b_ih, const float* __restrict__ b_hh, int n_nodes)
{
  __shared__ float As[32][64];    // 8 KB
  __shared__ float Bs[32][256];   // 32 KB
  const int tid = threadIdx.x;
  const int wave = tid >> 6;      // 0..7 -> rows wave*8..+7
  const int lane = tid & 63;      // feature f
  const int bm = blockIdx.x * 64;
  float acc[8][4] = {};

  const int mA = tid >> 3;        // 0..63
  const int kA = (tid & 7) * 4;   // 0..28
  const int arow = bm + mA;
  const bool avalid = arow < n_nodes;

  for (int chunk = 0; chunk < 4; ++chunk) {
    const float* Asrc = (chunk < 2) ? aggr : h;
    const int kbase = (chunk & 1) * 32;
    float4 a0 = make_float4(0, 0, 0, 0);
    if (avalid) a0 = *(const float4*)(Asrc + (size_t)arow * HID + kbase + kA);
    const float4* Bsrc = (const float4*)(Bbig_s + (size_t)chunk * 32 * 256);
    __syncthreads();
    As[kA + 0][mA] = a0.x; As[kA + 1][mA] = a0.y; As[kA + 2][mA] = a0.z; As[kA + 3][mA] = a0.w;
    float4* Bdst = (float4*)&Bs[0][0];
#pragma unroll
    for (int i = 0; i < 4; ++i) Bdst[tid + i * 512] = Bsrc[tid + i * 512];
    __syncthreads();
#pragma unroll 4
    for (int k = 0; k < 32; ++k) {
      float4 b = *(const float4*)&Bs[k][lane * 4];
      float4 am0 = *(const float4*)&As[k][wave * 8];
      float4 am1 = *(const float4*)&As[k][wave * 8 + 4];
      float a_[8] = {am0.x, am0.y, am0.z, am0.w, am1.x, am1.y, am1.z, am1.w};
#pragma unroll
      for (int r = 0; r < 8; ++r) {
        acc[r][0] += a_[r] * b.x; acc[r][1] += a_[r] * b.y;
        acc[r][2] += a_[r] * b.z; acc[r][3] += a_[r] * b.w;
      }
    }
  }

  const float bir = b_ih[lane], biz = b_ih[64 + lane], bin_ = b_ih[128 + lane];
  const float bhr = b_hh[lane], bhz = b_hh[64 + lane], bhn = b_hh[128 + lane];
#pragma unroll
  for (int r = 0; r < 8; ++r) {
    int row = bm + wave * 8 + r;
    if (row < n_nodes) {
      float hold = h[(size_t)row * HID + lane];
      float rg = sigmoidf_(acc[r][0] + bir + bhr);
      float zg = sigmoidf_(acc[r][1] + biz + bhz);
      float ng = tanhf(acc[r][2] + bin_ + rg * (acc[r][3] + bhn));
      h[(size_t)row * HID + lane] = (1.f - zg) * ng + zg * hold;
    }
  }
}

// ---------------- pooling ----------------
__global__ __launch_bounds__(256) void k_pool1(
    const float* __restrict__ h, const int* __restrict__ batch,
    const float* __restrict__ gate_w, const float* __restrict__ gate_b,
    const float* __restrict__ out_w, const float* __restrict__ out_b,
    float* __restrict__ gl, float* __restrict__ f2, unsigned* __restrict__ gmax, int n_nodes)
{
  __shared__ unsigned smax[64];
  if (threadIdx.x < 64) smax[threadIdx.x] = 0u;
  __syncthreads();
  int n = blockIdx.x * blockDim.x + threadIdx.x;
  if (n < n_nodes) {
    float g = gate_b[0], f0 = out_b[0], f1 = out_b[1];
    const float* hr = h + (size_t)n * HID;
    for (int k = 0; k < HID; ++k) {
      float hv = hr[k];
      g += hv * gate_w[k];
      f0 += hv * out_w[2 * k];
      f1 += hv * out_w[2 * k + 1];
    }
    gl[n] = g;
    f2[2 * n] = f0;
    f2[2 * n + 1] = f1;
    atomicMax(&smax[batch[n]], enc_f(g));
  }
  __syncthreads();
  if (threadIdx.x < 64 && smax[threadIdx.x] != 0u)
    atomicMax(&gmax[threadIdx.x], smax[threadIdx.x]);
}

__global__ __launch_bounds__(256) void k_pool2(
    const float* __restrict__ gl, const float* __restrict__ f2,
    const int* __restrict__ batch, const unsigned* __restrict__ gmax,
    float* __restrict__ acc3, int n_nodes)
{
  __shared__ float sacc[192];
  int t = threadIdx.x;
  if (t < 192) sacc[t] = 0.f;
  __syncthreads();
  int n = blockIdx.x * blockDim.x + t;
  if (n < n_nodes) {
    int b = batch[n];
    float e = expf(gl[n] - dec_f(gmax[b]));
    atomicAdd(&sacc[3 * b + 0], e);
    atomicAdd(&sacc[3 * b + 1], e * f2[2 * n]);
    atomicAdd(&sacc[3 * b + 2], e * f2[2 * n + 1]);
  }
  __syncthreads();
  if (t < 192) {
    float v = sacc[t];
    if (v != 0.f) atomicAdd(&acc3[t], v);
  }
}

__global__ void k_pool3(const float* __restrict__ acc3, float* __restrict__ out, int n_graphs) {
  int g = blockIdx.x * blockDim.x + threadIdx.x;
  if (g < n_graphs) {
    float s = acc3[3 * g] + 1e-16f;
    float p0 = acc3[3 * g + 1] / s, p1 = acc3[3 * g + 2] / s;
    float m = fmaxf(p0, p1);
    float e0 = expf(p0 - m), e1 = expf(p1 - m);
    float d = e0 + e1;
    out[2 * g] = e0 / d;
    out[2 * g + 1] = e1 / d;
  }
}

// ---------------- host ----------------
extern "C" void kernel_launch(void* const* d_in, const int* in_sizes, int n_in,
                              void* d_out, int out_size, void* d_ws, size_t ws_size,
                              hipStream_t stream)
{
  const float* x        = (const float*)d_in[0];
  const int*   edge     = (const int*)d_in[1];
  const int*   batch    = (const int*)d_in[2];
  const float* reduce_w = (const float*)d_in[3];
  const float* reduce_b = (const float*)d_in[4];
  const float* ggc_w    = (const float*)d_in[5];
  const float* w_ih     = (const float*)d_in[6];
  const float* w_hh     = (const float*)d_in[7];
  const float* b_ih     = (const float*)d_in[8];
  const float* b_hh     = (const float*)d_in[9];
  const float* gate_w   = (const float*)d_in[10];
  const float* gate_b   = (const float*)d_in[11];
  const float* out_w    = (const float*)d_in[12];
  const float* out_b    = (const float*)d_in[13];
  float* out = (float*)d_out;

  const int n_nodes  = in_sizes[0] / ANNOT;
  const int E        = in_sizes[1] / 2;
  const int n_graphs = out_size / 2;
  const int* src  = edge;
  const int* dstv = edge + E;

  // workspace layout (256B aligned)
  size_t off = 0;
  auto alloc = [&](size_t bytes) { size_t o = off; off = (off + bytes + 255) & ~(size_t)255; return o; };
  char* w = (char*)d_ws;
  const int NB = (n_nodes + 1023) / 1024;

  float* h       = (float*)(w + alloc((size_t)n_nodes * HID * 4));
  float* aggr    = (float*)(w + alloc((size_t)n_nodes * HID * 4));
  int*   csr_src = (int*)  (w + alloc((size_t)E * 4));
  int*   row_ptr = (int*)  (w + alloc((size_t)(n_nodes + 1) * 4));
  int*   cursor  = (int*)  (w + alloc((size_t)n_nodes * 4));
  int*   cnt     = (int*)  (w + alloc((size_t)n_nodes * 4));
  int*   bsum    = (int*)  (w + alloc((size_t)NB * 4));
  int*   boff    = (int*)  (w + alloc((size_t)NB * 4));
  float* Bbig    = (float*)(w + alloc((size_t)NSTEPS * 128 * 256 * 4));
  float* gl      = (float*)(w + alloc((size_t)n_nodes * 4));
  float* f2      = (float*)(w + alloc((size_t)n_nodes * 2 * 4));
  unsigned* gmax = (unsigned*)(w + alloc(256));
  float* acc3    = (float*)(w + alloc(192 * 4));
  (void)ws_size; (void)n_in;

  // zero-init
  hipMemsetAsync(cnt, 0, (size_t)n_nodes * 4, stream);
  hipMemsetAsync(gmax, 0, 256, stream);
  hipMemsetAsync(acc3, 0, 192 * 4, stream);

  const int gN64  = (n_nodes + 63) / 64;
  const int gE256 = (E + 255) / 256;
  const int gN256 = (n_nodes + 255) / 256;

  // h = x @ reduce_w + b
  k_reduce<<<gN64, 256, 0, stream>>>(x, reduce_w, reduce_b, h, n_nodes);
  // per-step combined weights
  k_bbig<<<dim3(128, NSTEPS), 256, 0, stream>>>(ggc_w, w_ih, w_hh, Bbig);
  // CSR by dst
  k_hist<<<gE256, 256, 0, stream>>>(dstv, E, cnt);
  k_scan1<<<NB, 1024, 0, stream>>>(cnt, n_nodes, bsum);
  k_scan2<<<1, 1, 0, stream>>>(bsum, NB, boff, row_ptr, n_nodes);
  k_scan3<<<NB, 1024, 0, stream>>>(cnt, n_nodes, boff, row_ptr, cursor);
  k_fill<<<gE256, 256, 0, stream>>>(src, dstv, E, cursor, csr_src);

  // 8 gated steps
  for (int s = 0; s < NSTEPS; ++s) {
    k_aggr<<<(n_nodes + 3) / 4, 256, 0, stream>>>(h, row_ptr, csr_src, aggr, n_nodes);
    k_gru<<<gN64, 512, 0, stream>>>(aggr, h, Bbig + (size_t)s * 128 * 256, b_ih, b_hh, n_nodes);
  }

  // pooling
  k_pool1<<<gN256, 256, 0, stream>>>(h, batch, gate_w, gate_b, out_w, out_b, gl, f2, gmax, n_nodes);
  k_pool2<<<gN256, 256, 0, stream>>>(gl, f2, batch, gmax, acc3, n_nodes);
  k_pool3<<<1, 64, 0, stream>>>(acc3, out, n_graphs);
}

// Round 2
// 1537.252 us; speedup vs baseline: 1.4453x; 1.4453x over previous
//
#include <hip/hip_runtime.h>
#include <math.h>

#define HID 64
#define ANNOT 512
#define NSTEPS 8

__device__ __forceinline__ float sigmoidf_(float x) { return 1.0f / (1.0f + __expf(-x)); }

__device__ __forceinline__ unsigned enc_f(float f) {
  unsigned u = __float_as_uint(f);
  return (f < 0.f) ? ~u : (u | 0x80000000u);
}
__device__ __forceinline__ float dec_f(unsigned u) {
  return (u & 0x80000000u) ? __uint_as_float(u & 0x7FFFFFFFu) : __uint_as_float(~u);
}

// ---------------- reduce GEMM: h[n,64] = x[n,512] @ Wr[512,64] + br ----------------
__global__ __launch_bounds__(256) void k_reduce(
    const float* __restrict__ x, const float* __restrict__ Wr,
    const float* __restrict__ br, float* __restrict__ h, int n_nodes)
{
  __shared__ float As[32][64];  // As[k][m] (x tile transposed)
  __shared__ float Bs[32][64];  // Bs[k][n]
  const int tid = threadIdx.x;
  const int tx = tid & 15, ty = tid >> 4;
  const int bm = blockIdx.x * 64;
  float acc[4][4] = {};
  const int mA = tid >> 2;
  const int kA = (tid & 3) * 8;
  const int kB = tid >> 3;
  const int nB = (tid & 7) * 8;
  const bool mvalid = (bm + mA) < n_nodes;
  const size_t rowA = (size_t)(bm + mA) * ANNOT;

  for (int kt = 0; kt < ANNOT; kt += 32) {
    float4 a0 = make_float4(0, 0, 0, 0), a1 = a0;
    if (mvalid) {
      a0 = *(const float4*)(x + rowA + kt + kA);
      a1 = *(const float4*)(x + rowA + kt + kA + 4);
    }
    float4 b0 = *(const float4*)(Wr + (size_t)(kt + kB) * HID + nB);
    float4 b1 = *(const float4*)(Wr + (size_t)(kt + kB) * HID + nB + 4);
    __syncthreads();
    As[kA + 0][mA] = a0.x; As[kA + 1][mA] = a0.y; As[kA + 2][mA] = a0.z; As[kA + 3][mA] = a0.w;
    As[kA + 4][mA] = a1.x; As[kA + 5][mA] = a1.y; As[kA + 6][mA] = a1.z; As[kA + 7][mA] = a1.w;
    *(float4*)&Bs[kB][nB] = b0;
    *(float4*)&Bs[kB][nB + 4] = b1;
    __syncthreads();
#pragma unroll
    for (int k = 0; k < 32; ++k) {
      float4 av = *(const float4*)&As[k][ty * 4];
      float4 bv = *(const float4*)&Bs[k][tx * 4];
      acc[0][0] += av.x * bv.x; acc[0][1] += av.x * bv.y; acc[0][2] += av.x * bv.z; acc[0][3] += av.x * bv.w;
      acc[1][0] += av.y * bv.x; acc[1][1] += av.y * bv.y; acc[1][2] += av.y * bv.z; acc[1][3] += av.y * bv.w;
      acc[2][0] += av.z * bv.x; acc[2][1] += av.z * bv.y; acc[2][2] += av.z * bv.z; acc[2][3] += av.z * bv.w;
      acc[3][0] += av.w * bv.x; acc[3][1] += av.w * bv.y; acc[3][2] += av.w * bv.z; acc[3][3] += av.w * bv.w;
    }
  }
  float4 bias = *(const float4*)(br + tx * 4);
#pragma unroll
  for (int i = 0; i < 4; ++i) {
    int row = bm + ty * 4 + i;
    if (row < n_nodes) {
      float4 o;
      o.x = acc[i][0] + bias.x; o.y = acc[i][1] + bias.y;
      o.z = acc[i][2] + bias.z; o.w = acc[i][3] + bias.w;
      *(float4*)(h + (size_t)row * HID + tx * 4) = o;
    }
  }
}

// ------------- Bbig precompute: [8][128][256], col c = f*4+sec (interleaved) -------------
__global__ void k_bbig(const float* __restrict__ ggc_w, const float* __restrict__ w_ih,
                       const float* __restrict__ w_hh, float* __restrict__ Bbig)
{
  int s = blockIdx.y;
  int k = blockIdx.x;       // 0..127
  int c = threadIdx.x;      // 0..255
  int f = c >> 2, sec = c & 3;
  float v = 0.f;
  if (k < 64) {
    if (sec < 3) {
      const float* Ws = ggc_w + ((size_t)s * 64 + k) * 64;
      const float* wr = w_ih + (size_t)(sec * 64 + f) * 64;
      float a = 0.f;
      for (int j = 0; j < 64; ++j) a += Ws[j] * wr[j];
      v = a;
    }
  } else {
    int k2 = k - 64;
    if (sec == 0)      v = w_hh[(size_t)f * 64 + k2];
    else if (sec == 1) v = w_hh[(size_t)(64 + f) * 64 + k2];
    else if (sec == 3) v = w_hh[(size_t)(128 + f) * 64 + k2];
  }
  Bbig[((size_t)s * 128 + k) * 256 + c] = v;
}

// ---------------- CSR build ----------------
__global__ void k_hist(const int* __restrict__ dstv, int E, int* __restrict__ cnt) {
  int e = blockIdx.x * blockDim.x + threadIdx.x;
  if (e < E) atomicAdd(&cnt[dstv[e]], 1);
}

__global__ __launch_bounds__(1024) void k_scan1(const int* __restrict__ cnt, int n, int* __restrict__ bsum) {
  __shared__ int sd[1024];
  int i = blockIdx.x * 1024 + threadIdx.x;
  sd[threadIdx.x] = (i < n) ? cnt[i] : 0;
  __syncthreads();
  for (int s = 512; s > 0; s >>= 1) {
    if (threadIdx.x < s) sd[threadIdx.x] += sd[threadIdx.x + s];
    __syncthreads();
  }
  if (threadIdx.x == 0) bsum[blockIdx.x] = sd[0];
}

__global__ void k_scan2(const int* __restrict__ bsum, int nb, int* __restrict__ boff,
                        int* __restrict__ row_ptr, int n_nodes) {
  if (threadIdx.x == 0 && blockIdx.x == 0) {
    int run = 0;
    for (int b = 0; b < nb; ++b) { boff[b] = run; run += bsum[b]; }
    row_ptr[n_nodes] = run;
  }
}

__global__ __launch_bounds__(1024) void k_scan3(const int* __restrict__ cnt, int n,
                                                const int* __restrict__ boff,
                                                int* __restrict__ row_ptr, int* __restrict__ cursor) {
  __shared__ int sd[1024];
  int i = blockIdx.x * 1024 + threadIdx.x;
  int v = (i < n) ? cnt[i] : 0;
  sd[threadIdx.x] = v;
  __syncthreads();
  for (int d = 1; d < 1024; d <<= 1) {
    int t = (threadIdx.x >= d) ? sd[threadIdx.x - d] : 0;
    __syncthreads();
    sd[threadIdx.x] += t;
    __syncthreads();
  }
  if (i < n) {
    int excl = boff[blockIdx.x] + sd[threadIdx.x] - v;
    row_ptr[i] = excl;
    cursor[i] = excl;
  }
}

__global__ void k_fill(const int* __restrict__ src, const int* __restrict__ dstv, int E,
                       int* __restrict__ cursor, int* __restrict__ csr_src) {
  int e = blockIdx.x * blockDim.x + threadIdx.x;
  if (e < E) {
    int d = dstv[e];
    int pos = atomicAdd(&cursor[d], 1);
    csr_src[pos] = src[e];
  }
}

// ---------------- per-step: CSR gather-sum of h (MLP-optimized) ----------------
// wave = 1 node; 4 x 16-lane groups each gather a DIFFERENT edge's row as float4;
// 2x unroll -> 8 independent 256B gathers in flight per wave. Butterfly-reduce at end.
__global__ __launch_bounds__(256) void k_aggr(
    const float4* __restrict__ h4, const int* __restrict__ row_ptr,
    const int* __restrict__ csr_src, float4* __restrict__ aggr4, int n_nodes)
{
  const int wid = threadIdx.x >> 6;
  const int lane = threadIdx.x & 63;
  const int grp = lane >> 4;       // edge slot 0..3
  const int l16 = lane & 15;       // column quad 0..15
  const int n = blockIdx.x * 4 + wid;
  if (n >= n_nodes) return;
  const int beg = row_ptr[n], end = row_ptr[n + 1];
  float4 acc = make_float4(0.f, 0.f, 0.f, 0.f);

  int e = beg + grp;
  for (; e + 4 < end; e += 8) {
    int s0 = csr_src[e];
    int s1 = csr_src[e + 4];
    float4 v0 = h4[(size_t)s0 * 16 + l16];
    float4 v1 = h4[(size_t)s1 * 16 + l16];
    acc.x += v0.x + v1.x;
    acc.y += v0.y + v1.y;
    acc.z += v0.z + v1.z;
    acc.w += v0.w + v1.w;
  }
  if (e < end) {
    int s0 = csr_src[e];
    float4 v0 = h4[(size_t)s0 * 16 + l16];
    acc.x += v0.x; acc.y += v0.y; acc.z += v0.z; acc.w += v0.w;
  }

  // reduce across the 4 groups (xor 16, then 32)
  acc.x += __shfl_xor(acc.x, 16); acc.y += __shfl_xor(acc.y, 16);
  acc.z += __shfl_xor(acc.z, 16); acc.w += __shfl_xor(acc.w, 16);
  acc.x += __shfl_xor(acc.x, 32); acc.y += __shfl_xor(acc.y, 32);
  acc.z += __shfl_xor(acc.z, 32); acc.w += __shfl_xor(acc.w, 32);

  if (lane < 16) aggr4[(size_t)n * 16 + l16] = acc;
}

// ---------------- per-step: fused dual-GEMM + GRU gates (in-place h update) ----------------
__global__ __launch_bounds__(512) void k_gru(
    const float* __restrict__ aggr, float* __restrict__ h,
    const float* __restrict__ Bbig_s,
    const float* __restrict__ b_ih, const float* __restrict__ b_hh, int n_nodes)
{
  __shared__ float As[32][64];    // 8 KB
  __shared__ float Bs[32][256];   // 32 KB
  const int tid = threadIdx.x;
  const int wave = tid >> 6;
  const int lane = tid & 63;
  const int bm = blockIdx.x * 64;
  float acc[8][4] = {};

  const int mA = tid >> 3;
  const int kA = (tid & 7) * 4;
  const int arow = bm + mA;
  const bool avalid = arow < n_nodes;

  for (int chunk = 0; chunk < 4; ++chunk) {
    const float* Asrc = (chunk < 2) ? aggr : h;
    const int kbase = (chunk & 1) * 32;
    float4 a0 = make_float4(0, 0, 0, 0);
    if (avalid) a0 = *(const float4*)(Asrc + (size_t)arow * HID + kbase + kA);
    const float4* Bsrc = (const float4*)(Bbig_s + (size_t)chunk * 32 * 256);
    __syncthreads();
    As[kA + 0][mA] = a0.x; As[kA + 1][mA] = a0.y; As[kA + 2][mA] = a0.z; As[kA + 3][mA] = a0.w;
    float4* Bdst = (float4*)&Bs[0][0];
#pragma unroll
    for (int i = 0; i < 4; ++i) Bdst[tid + i * 512] = Bsrc[tid + i * 512];
    __syncthreads();
#pragma unroll 4
    for (int k = 0; k < 32; ++k) {
      float4 b = *(const float4*)&Bs[k][lane * 4];
      float4 am0 = *(const float4*)&As[k][wave * 8];
      float4 am1 = *(const float4*)&As[k][wave * 8 + 4];
      float a_[8] = {am0.x, am0.y, am0.z, am0.w, am1.x, am1.y, am1.z, am1.w};
#pragma unroll
      for (int r = 0; r < 8; ++r) {
        acc[r][0] += a_[r] * b.x; acc[r][1] += a_[r] * b.y;
        acc[r][2] += a_[r] * b.z; acc[r][3] += a_[r] * b.w;
      }
    }
  }

  const float bir = b_ih[lane], biz = b_ih[64 + lane], bin_ = b_ih[128 + lane];
  const float bhr = b_hh[lane], bhz = b_hh[64 + lane], bhn = b_hh[128 + lane];
#pragma unroll
  for (int r = 0; r < 8; ++r) {
    int row = bm + wave * 8 + r;
    if (row < n_nodes) {
      float hold = h[(size_t)row * HID + lane];
      float rg = sigmoidf_(acc[r][0] + bir + bhr);
      float zg = sigmoidf_(acc[r][1] + biz + bhz);
      float ng = tanhf(acc[r][2] + bin_ + rg * (acc[r][3] + bhn));
      h[(size_t)row * HID + lane] = (1.f - zg) * ng + zg * hold;
    }
  }
}

// ---------------- pooling ----------------
__global__ __launch_bounds__(256) void k_pool1(
    const float* __restrict__ h, const int* __restrict__ batch,
    const float* __restrict__ gate_w, const float* __restrict__ gate_b,
    const float* __restrict__ out_w, const float* __restrict__ out_b,
    float* __restrict__ gl, float* __restrict__ f2, unsigned* __restrict__ gmax, int n_nodes)
{
  __shared__ unsigned smax[64];
  if (threadIdx.x < 64) smax[threadIdx.x] = 0u;
  __syncthreads();
  int n = blockIdx.x * blockDim.x + threadIdx.x;
  if (n < n_nodes) {
    float g = gate_b[0], f0 = out_b[0], f1 = out_b[1];
    const float* hr = h + (size_t)n * HID;
    for (int k = 0; k < HID; ++k) {
      float hv = hr[k];
      g += hv * gate_w[k];
      f0 += hv * out_w[2 * k];
      f1 += hv * out_w[2 * k + 1];
    }
    gl[n] = g;
    f2[2 * n] = f0;
    f2[2 * n + 1] = f1;
    atomicMax(&smax[batch[n]], enc_f(g));
  }
  __syncthreads();
  if (threadIdx.x < 64 && smax[threadIdx.x] != 0u)
    atomicMax(&gmax[threadIdx.x], smax[threadIdx.x]);
}

__global__ __launch_bounds__(256) void k_pool2(
    const float* __restrict__ gl, const float* __restrict__ f2,
    const int* __restrict__ batch, const unsigned* __restrict__ gmax,
    float* __restrict__ acc3, int n_nodes)
{
  __shared__ float sacc[192];
  int t = threadIdx.x;
  if (t < 192) sacc[t] = 0.f;
  __syncthreads();
  int n = blockIdx.x * blockDim.x + t;
  if (n < n_nodes) {
    int b = batch[n];
    float e = expf(gl[n] - dec_f(gmax[b]));
    atomicAdd(&sacc[3 * b + 0], e);
    atomicAdd(&sacc[3 * b + 1], e * f2[2 * n]);
    atomicAdd(&sacc[3 * b + 2], e * f2[2 * n + 1]);
  }
  __syncthreads();
  if (t < 192) {
    float v = sacc[t];
    if (v != 0.f) atomicAdd(&acc3[t], v);
  }
}

__global__ void k_pool3(const float* __restrict__ acc3, float* __restrict__ out, int n_graphs) {
  int g = blockIdx.x * blockDim.x + threadIdx.x;
  if (g < n_graphs) {
    float s = acc3[3 * g] + 1e-16f;
    float p0 = acc3[3 * g + 1] / s, p1 = acc3[3 * g + 2] / s;
    float m = fmaxf(p0, p1);
    float e0 = expf(p0 - m), e1 = expf(p1 - m);
    float d = e0 + e1;
    out[2 * g] = e0 / d;
    out[2 * g + 1] = e1 / d;
  }
}

// ---------------- host ----------------
extern "C" void kernel_launch(void* const* d_in, const int* in_sizes, int n_in,
                              void* d_out, int out_size, void* d_ws, size_t ws_size,
                              hipStream_t stream)
{
  const float* x        = (const float*)d_in[0];
  const int*   edge     = (const int*)d_in[1];
  const int*   batch    = (const int*)d_in[2];
  const float* reduce_w = (const float*)d_in[3];
  const float* reduce_b = (const float*)d_in[4];
  const float* ggc_w    = (const float*)d_in[5];
  const float* w_ih     = (const float*)d_in[6];
  const float* w_hh     = (const float*)d_in[7];
  const float* b_ih     = (const float*)d_in[8];
  const float* b_hh     = (const float*)d_in[9];
  const float* gate_w   = (const float*)d_in[10];
  const float* gate_b   = (const float*)d_in[11];
  const float* out_w    = (const float*)d_in[12];
  const float* out_b    = (const float*)d_in[13];
  float* out = (float*)d_out;

  const int n_nodes  = in_sizes[0] / ANNOT;
  const int E        = in_sizes[1] / 2;
  const int n_graphs = out_size / 2;
  const int* src  = edge;
  const int* dstv = edge + E;

  size_t off = 0;
  auto alloc = [&](size_t bytes) { size_t o = off; off = (off + bytes + 255) & ~(size_t)255; return o; };
  char* w = (char*)d_ws;
  const int NB = (n_nodes + 1023) / 1024;

  float* h       = (float*)(w + alloc((size_t)n_nodes * HID * 4));
  float* aggr    = (float*)(w + alloc((size_t)n_nodes * HID * 4));
  int*   csr_src = (int*)  (w + alloc((size_t)E * 4));
  int*   row_ptr = (int*)  (w + alloc((size_t)(n_nodes + 1) * 4));
  int*   cursor  = (int*)  (w + alloc((size_t)n_nodes * 4));
  int*   cnt     = (int*)  (w + alloc((size_t)n_nodes * 4));
  int*   bsum    = (int*)  (w + alloc((size_t)NB * 4));
  int*   boff    = (int*)  (w + alloc((size_t)NB * 4));
  float* Bbig    = (float*)(w + alloc((size_t)NSTEPS * 128 * 256 * 4));
  float* gl      = (float*)(w + alloc((size_t)n_nodes * 4));
  float* f2      = (float*)(w + alloc((size_t)n_nodes * 2 * 4));
  unsigned* gmax = (unsigned*)(w + alloc(256));
  float* acc3    = (float*)(w + alloc(192 * 4));
  (void)ws_size; (void)n_in;

  hipMemsetAsync(cnt, 0, (size_t)n_nodes * 4, stream);
  hipMemsetAsync(gmax, 0, 256, stream);
  hipMemsetAsync(acc3, 0, 192 * 4, stream);

  const int gN64  = (n_nodes + 63) / 64;
  const int gE256 = (E + 255) / 256;
  const int gN256 = (n_nodes + 255) / 256;

  k_reduce<<<gN64, 256, 0, stream>>>(x, reduce_w, reduce_b, h, n_nodes);
  k_bbig<<<dim3(128, NSTEPS), 256, 0, stream>>>(ggc_w, w_ih, w_hh, Bbig);
  k_hist<<<gE256, 256, 0, stream>>>(dstv, E, cnt);
  k_scan1<<<NB, 1024, 0, stream>>>(cnt, n_nodes, bsum);
  k_scan2<<<1, 1, 0, stream>>>(bsum, NB, boff, row_ptr, n_nodes);
  k_scan3<<<NB, 1024, 0, stream>>>(cnt, n_nodes, boff, row_ptr, cursor);
  k_fill<<<gE256, 256, 0, stream>>>(src, dstv, E, cursor, csr_src);

  for (int s = 0; s < NSTEPS; ++s) {
    k_aggr<<<(n_nodes + 3) / 4, 256, 0, stream>>>((const float4*)h, row_ptr, csr_src, (float4*)aggr, n_nodes);
    k_gru<<<gN64, 512, 0, stream>>>(aggr, h, Bbig + (size_t)s * 128 * 256, b_ih, b_hh, n_nodes);
  }

  k_pool1<<<gN256, 256, 0, stream>>>(h, batch, gate_w, gate_b, out_w, out_b, gl, f2, gmax, n_nodes);
  k_pool2<<<gN256, 256, 0, stream>>>(gl, f2, batch, gmax, acc3, n_nodes);
  k_pool3<<<1, 64, 0, stream>>>(acc3, out, n_graphs);
}

// Round 3
// 954.885 us; speedup vs baseline: 2.3268x; 1.6099x over previous
//
#include <hip/hip_runtime.h>
#include <math.h>

#define HID 64
#define ANNOT 512
#define NSTEPS 8

typedef __attribute__((ext_vector_type(8))) short short8_t;
typedef __attribute__((ext_vector_type(16))) float floatx16;

__device__ __forceinline__ float sigmoidf_(float x) { return 1.0f / (1.0f + __expf(-x)); }

__device__ __forceinline__ float bf2f(unsigned short u) {
  return __uint_as_float(((unsigned)u) << 16);
}
__device__ __forceinline__ unsigned short f2bf(float f) {
  unsigned u = __float_as_uint(f);
  unsigned r = ((u >> 16) & 1u) + 0x7fffu;
  return (unsigned short)((u + r) >> 16);
}

__device__ __forceinline__ unsigned enc_f(float f) {
  unsigned u = __float_as_uint(f);
  return (f < 0.f) ? ~u : (u | 0x80000000u);
}
__device__ __forceinline__ float dec_f(unsigned u) {
  return (u & 0x80000000u) ? __uint_as_float(u & 0x7FFFFFFFu) : __uint_as_float(~u);
}

// ---------------- reduce GEMM: h[n,64] = x[n,512] @ Wr[512,64] + br  (h stored bf16) ----------------
__global__ __launch_bounds__(256) void k_reduce(
    const float* __restrict__ x, const float* __restrict__ Wr,
    const float* __restrict__ br, unsigned short* __restrict__ h, int n_nodes)
{
  __shared__ float As[32][64];
  __shared__ float Bs[32][64];
  const int tid = threadIdx.x;
  const int tx = tid & 15, ty = tid >> 4;
  const int bm = blockIdx.x * 64;
  float acc[4][4] = {};
  const int mA = tid >> 2;
  const int kA = (tid & 3) * 8;
  const int kB = tid >> 3;
  const int nB = (tid & 7) * 8;
  const bool mvalid = (bm + mA) < n_nodes;
  const size_t rowA = (size_t)(bm + mA) * ANNOT;

  for (int kt = 0; kt < ANNOT; kt += 32) {
    float4 a0 = make_float4(0, 0, 0, 0), a1 = a0;
    if (mvalid) {
      a0 = *(const float4*)(x + rowA + kt + kA);
      a1 = *(const float4*)(x + rowA + kt + kA + 4);
    }
    float4 b0 = *(const float4*)(Wr + (size_t)(kt + kB) * HID + nB);
    float4 b1 = *(const float4*)(Wr + (size_t)(kt + kB) * HID + nB + 4);
    __syncthreads();
    As[kA + 0][mA] = a0.x; As[kA + 1][mA] = a0.y; As[kA + 2][mA] = a0.z; As[kA + 3][mA] = a0.w;
    As[kA + 4][mA] = a1.x; As[kA + 5][mA] = a1.y; As[kA + 6][mA] = a1.z; As[kA + 7][mA] = a1.w;
    *(float4*)&Bs[kB][nB] = b0;
    *(float4*)&Bs[kB][nB + 4] = b1;
    __syncthreads();
#pragma unroll
    for (int k = 0; k < 32; ++k) {
      float4 av = *(const float4*)&As[k][ty * 4];
      float4 bv = *(const float4*)&Bs[k][tx * 4];
      acc[0][0] += av.x * bv.x; acc[0][1] += av.x * bv.y; acc[0][2] += av.x * bv.z; acc[0][3] += av.x * bv.w;
      acc[1][0] += av.y * bv.x; acc[1][1] += av.y * bv.y; acc[1][2] += av.y * bv.z; acc[1][3] += av.y * bv.w;
      acc[2][0] += av.z * bv.x; acc[2][1] += av.z * bv.y; acc[2][2] += av.z * bv.z; acc[2][3] += av.z * bv.w;
      acc[3][0] += av.w * bv.x; acc[3][1] += av.w * bv.y; acc[3][2] += av.w * bv.z; acc[3][3] += av.w * bv.w;
    }
  }
  float4 bias = *(const float4*)(br + tx * 4);
#pragma unroll
  for (int i = 0; i < 4; ++i) {
    int row = bm + ty * 4 + i;
    if (row < n_nodes) {
      ushort4 o;
      o.x = f2bf(acc[i][0] + bias.x);
      o.y = f2bf(acc[i][1] + bias.y);
      o.z = f2bf(acc[i][2] + bias.z);
      o.w = f2bf(acc[i][3] + bias.w);
      *(ushort4*)(h + (size_t)row * HID + tx * 4) = o;
    }
  }
}

// ------------- Bpack precompute: MFMA-fragment layout, bf16 -------------
// B[k=0..127][c=0..255], c = sec*64 + f (sec-major).
//   k<64 (aggr part):  sec<3: (W_s @ w_ih_sec^T)[k][f]; sec3: 0
//   k>=64 (h part):    sec0: w_hh[f][k2]; sec1: w_hh[64+f][k2]; sec2: 0; sec3: w_hh[128+f][k2]
// Fragment for 32x32x16: lane l holds B[kc*16 + (l>>5)*8 + j][nt*32 + (l&31)], j=0..7
// Bpack[s][kc][nt][l][j]
__global__ void k_bbig(const float* __restrict__ ggc_w, const float* __restrict__ w_ih,
                       const float* __restrict__ w_hh, unsigned short* __restrict__ Bpack)
{
  const int nt = blockIdx.x;   // 0..7
  const int kc = blockIdx.y;   // 0..7
  const int s  = blockIdx.z;   // 0..7
  const int l  = threadIdx.x;  // 0..63
  const int c = nt * 32 + (l & 31);
  const int sec = c >> 6, f = c & 63;
  unsigned short outv[8];
#pragma unroll
  for (int j = 0; j < 8; ++j) {
    int k = kc * 16 + (l >> 5) * 8 + j;
    float v = 0.f;
    if (k < 64) {
      if (sec < 3) {
        const float* Ws = ggc_w + ((size_t)s * 64 + k) * 64;
        const float* wr = w_ih + (size_t)(sec * 64 + f) * 64;
        float a = 0.f;
        for (int q = 0; q < 64; ++q) a += Ws[q] * wr[q];
        v = a;
      }
    } else {
      int k2 = k - 64;
      if (sec == 0)      v = w_hh[(size_t)f * 64 + k2];
      else if (sec == 1) v = w_hh[(size_t)(64 + f) * 64 + k2];
      else if (sec == 3) v = w_hh[(size_t)(128 + f) * 64 + k2];
    }
    outv[j] = f2bf(v);
  }
  unsigned short* dst = Bpack + ((((size_t)s * 8 + kc) * 8 + nt) * 64 + l) * 8;
#pragma unroll
  for (int j = 0; j < 8; ++j) dst[j] = outv[j];
}

// ---------------- CSR build ----------------
__global__ void k_hist(const int* __restrict__ dstv, int E, int* __restrict__ cnt) {
  int e = blockIdx.x * blockDim.x + threadIdx.x;
  if (e < E) atomicAdd(&cnt[dstv[e]], 1);
}

__global__ __launch_bounds__(1024) void k_scan1(const int* __restrict__ cnt, int n, int* __restrict__ bsum) {
  __shared__ int sd[1024];
  int i = blockIdx.x * 1024 + threadIdx.x;
  sd[threadIdx.x] = (i < n) ? cnt[i] : 0;
  __syncthreads();
  for (int s = 512; s > 0; s >>= 1) {
    if (threadIdx.x < s) sd[threadIdx.x] += sd[threadIdx.x + s];
    __syncthreads();
  }
  if (threadIdx.x == 0) bsum[blockIdx.x] = sd[0];
}

__global__ void k_scan2(const int* __restrict__ bsum, int nb, int* __restrict__ boff,
                        int* __restrict__ row_ptr, int n_nodes) {
  if (threadIdx.x == 0 && blockIdx.x == 0) {
    int run = 0;
    for (int b = 0; b < nb; ++b) { boff[b] = run; run += bsum[b]; }
    row_ptr[n_nodes] = run;
  }
}

__global__ __launch_bounds__(1024) void k_scan3(const int* __restrict__ cnt, int n,
                                                const int* __restrict__ boff,
                                                int* __restrict__ row_ptr, int* __restrict__ cursor) {
  __shared__ int sd[1024];
  int i = blockIdx.x * 1024 + threadIdx.x;
  int v = (i < n) ? cnt[i] : 0;
  sd[threadIdx.x] = v;
  __syncthreads();
  for (int d = 1; d < 1024; d <<= 1) {
    int t = (threadIdx.x >= d) ? sd[threadIdx.x - d] : 0;
    __syncthreads();
    sd[threadIdx.x] += t;
    __syncthreads();
  }
  if (i < n) {
    int excl = boff[blockIdx.x] + sd[threadIdx.x] - v;
    row_ptr[i] = excl;
    cursor[i] = excl;
  }
}

__global__ void k_fill(const int* __restrict__ src, const int* __restrict__ dstv, int E,
                       int* __restrict__ cursor, int* __restrict__ csr_src) {
  int e = blockIdx.x * blockDim.x + threadIdx.x;
  if (e < E) {
    int d = dstv[e];
    int pos = atomicAdd(&cursor[d], 1);
    csr_src[pos] = src[e];
  }
}

// ---------------- per-step: CSR gather-sum of h (bf16 rows, MLP-optimized) ----------------
// wave = 1 node; 4 x 16-lane groups each gather a DIFFERENT edge's 128B bf16 row (8B/lane);
// 2x unroll -> 8 independent gathers in flight. Butterfly-reduce, store bf16.
__global__ __launch_bounds__(256) void k_aggr(
    const ushort4* __restrict__ h4, const int* __restrict__ row_ptr,
    const int* __restrict__ csr_src, ushort4* __restrict__ aggr4, int n_nodes)
{
  const int wid = threadIdx.x >> 6;
  const int lane = threadIdx.x & 63;
  const int grp = lane >> 4;
  const int l16 = lane & 15;
  const int n = blockIdx.x * 4 + wid;
  if (n >= n_nodes) return;
  const int beg = row_ptr[n], end = row_ptr[n + 1];
  float a0 = 0.f, a1 = 0.f, a2 = 0.f, a3 = 0.f;

  int e = beg + grp;
  for (; e + 4 < end; e += 8) {
    int s0 = csr_src[e];
    int s1 = csr_src[e + 4];
    ushort4 v0 = h4[(size_t)s0 * 16 + l16];
    ushort4 v1 = h4[(size_t)s1 * 16 + l16];
    a0 += bf2f(v0.x) + bf2f(v1.x);
    a1 += bf2f(v0.y) + bf2f(v1.y);
    a2 += bf2f(v0.z) + bf2f(v1.z);
    a3 += bf2f(v0.w) + bf2f(v1.w);
  }
  if (e < end) {
    int s0 = csr_src[e];
    ushort4 v0 = h4[(size_t)s0 * 16 + l16];
    a0 += bf2f(v0.x); a1 += bf2f(v0.y); a2 += bf2f(v0.z); a3 += bf2f(v0.w);
  }

  a0 += __shfl_xor(a0, 16); a1 += __shfl_xor(a1, 16);
  a2 += __shfl_xor(a2, 16); a3 += __shfl_xor(a3, 16);
  a0 += __shfl_xor(a0, 32); a1 += __shfl_xor(a1, 32);
  a2 += __shfl_xor(a2, 32); a3 += __shfl_xor(a3, 32);

  if (lane < 16) {
    ushort4 o;
    o.x = f2bf(a0); o.y = f2bf(a1); o.z = f2bf(a2); o.w = f2bf(a3);
    aggr4[(size_t)n * 16 + l16] = o;
  }
}

// ---------------- per-step: MFMA dual-GEMM + GRU gates (in-place bf16 h update) ----------------
// Block = 4 waves x 32 rows = 128 rows. Per wave: C[32][256] = [aggr|h](32x128) @ B(128x256).
// A frags from global (own rows only), B frags from packed L2-resident Bpack. No LDS, no syncs.
__global__ __launch_bounds__(256) void k_gru(
    const unsigned short* __restrict__ aggr, unsigned short* __restrict__ h,
    const unsigned short* __restrict__ Bpack_s,
    const float* __restrict__ b_ih, const float* __restrict__ b_hh, int n_nodes)
{
  const int wave = threadIdx.x >> 6;
  const int lane = threadIdx.x & 63;
  const int hi = lane >> 5;
  const int l31 = lane & 31;
  const int rbase = blockIdx.x * 128 + wave * 32;
  const int arow = rbase + l31;
  const bool avalid = arow < n_nodes;

  floatx16 acc[8];
#pragma unroll
  for (int nt = 0; nt < 8; ++nt)
#pragma unroll
    for (int j = 0; j < 16; ++j) acc[nt][j] = 0.f;

#pragma unroll
  for (int kc = 0; kc < 8; ++kc) {
    const unsigned short* Asrc = (kc < 4) ? aggr : h;
    short8_t a = {0, 0, 0, 0, 0, 0, 0, 0};
    if (avalid)
      a = *(const short8_t*)(Asrc + (size_t)arow * HID + (kc & 3) * 16 + hi * 8);
    const short8_t* Bb = (const short8_t*)(Bpack_s + (size_t)kc * 8 * 64 * 8);
#pragma unroll
    for (int nt = 0; nt < 8; ++nt) {
      short8_t b = Bb[nt * 64 + lane];
      acc[nt] = __builtin_amdgcn_mfma_f32_32x32x16_bf16(a, b, acc[nt], 0, 0, 0);
    }
  }

  // GRU epilogue: sec-major cols -> acc[half]=r, acc[2+half]=z, acc[4+half]=i_n, acc[6+half]=h_n
  float bi[2][3], bh[2][3];
#pragma unroll
  for (int half = 0; half < 2; ++half) {
    int f = half * 32 + l31;
    bi[half][0] = b_ih[f]; bi[half][1] = b_ih[64 + f]; bi[half][2] = b_ih[128 + f];
    bh[half][0] = b_hh[f]; bh[half][1] = b_hh[64 + f]; bh[half][2] = b_hh[128 + f];
  }
#pragma unroll
  for (int reg = 0; reg < 16; ++reg) {
    int row = rbase + (reg & 3) + 8 * (reg >> 2) + 4 * hi;
    if (row < n_nodes) {
#pragma unroll
      for (int half = 0; half < 2; ++half) {
        int f = half * 32 + l31;
        float rg = sigmoidf_(acc[half][reg] + bi[half][0] + bh[half][0]);
        float zg = sigmoidf_(acc[2 + half][reg] + bi[half][1] + bh[half][1]);
        float ng = tanhf(acc[4 + half][reg] + bi[half][2] + rg * (acc[6 + half][reg] + bh[half][2]));
        size_t idx = (size_t)row * HID + f;
        float hold = bf2f(h[idx]);
        h[idx] = f2bf((1.f - zg) * ng + zg * hold);
      }
    }
  }
}

// ---------------- pooling ----------------
__global__ __launch_bounds__(256) void k_pool1(
    const unsigned short* __restrict__ h, const int* __restrict__ batch,
    const float* __restrict__ gate_w, const float* __restrict__ gate_b,
    const float* __restrict__ out_w, const float* __restrict__ out_b,
    float* __restrict__ gl, float* __restrict__ f2, unsigned* __restrict__ gmax, int n_nodes)
{
  __shared__ unsigned smax[64];
  if (threadIdx.x < 64) smax[threadIdx.x] = 0u;
  __syncthreads();
  int n = blockIdx.x * blockDim.x + threadIdx.x;
  if (n < n_nodes) {
    float g = gate_b[0], f0 = out_b[0], f1 = out_b[1];
    const ushort4* hr = (const ushort4*)(h + (size_t)n * HID);
#pragma unroll
    for (int q = 0; q < 16; ++q) {
      ushort4 v = hr[q];
      float h0 = bf2f(v.x), h1 = bf2f(v.y), h2 = bf2f(v.z), h3 = bf2f(v.w);
      int k = q * 4;
      g += h0 * gate_w[k] + h1 * gate_w[k + 1] + h2 * gate_w[k + 2] + h3 * gate_w[k + 3];
      f0 += h0 * out_w[2 * k] + h1 * out_w[2 * k + 2] + h2 * out_w[2 * k + 4] + h3 * out_w[2 * k + 6];
      f1 += h0 * out_w[2 * k + 1] + h1 * out_w[2 * k + 3] + h2 * out_w[2 * k + 5] + h3 * out_w[2 * k + 7];
    }
    gl[n] = g;
    f2[2 * n] = f0;
    f2[2 * n + 1] = f1;
    atomicMax(&smax[batch[n]], enc_f(g));
  }
  __syncthreads();
  if (threadIdx.x < 64 && smax[threadIdx.x] != 0u)
    atomicMax(&gmax[threadIdx.x], smax[threadIdx.x]);
}

__global__ __launch_bounds__(256) void k_pool2(
    const float* __restrict__ gl, const float* __restrict__ f2,
    const int* __restrict__ batch, const unsigned* __restrict__ gmax,
    float* __restrict__ acc3, int n_nodes)
{
  __shared__ float sacc[192];
  int t = threadIdx.x;
  if (t < 192) sacc[t] = 0.f;
  __syncthreads();
  int n = blockIdx.x * blockDim.x + t;
  if (n < n_nodes) {
    int b = batch[n];
    float e = expf(gl[n] - dec_f(gmax[b]));
    atomicAdd(&sacc[3 * b + 0], e);
    atomicAdd(&sacc[3 * b + 1], e * f2[2 * n]);
    atomicAdd(&sacc[3 * b + 2], e * f2[2 * n + 1]);
  }
  __syncthreads();
  if (t < 192) {
    float v = sacc[t];
    if (v != 0.f) atomicAdd(&acc3[t], v);
  }
}

__global__ void k_pool3(const float* __restrict__ acc3, float* __restrict__ out, int n_graphs) {
  int g = blockIdx.x * blockDim.x + threadIdx.x;
  if (g < n_graphs) {
    float s = acc3[3 * g] + 1e-16f;
    float p0 = acc3[3 * g + 1] / s, p1 = acc3[3 * g + 2] / s;
    float m = fmaxf(p0, p1);
    float e0 = expf(p0 - m), e1 = expf(p1 - m);
    float d = e0 + e1;
    out[2 * g] = e0 / d;
    out[2 * g + 1] = e1 / d;
  }
}

// ---------------- host ----------------
extern "C" void kernel_launch(void* const* d_in, const int* in_sizes, int n_in,
                              void* d_out, int out_size, void* d_ws, size_t ws_size,
                              hipStream_t stream)
{
  const float* x        = (const float*)d_in[0];
  const int*   edge     = (const int*)d_in[1];
  const int*   batch    = (const int*)d_in[2];
  const float* reduce_w = (const float*)d_in[3];
  const float* reduce_b = (const float*)d_in[4];
  const float* ggc_w    = (const float*)d_in[5];
  const float* w_ih     = (const float*)d_in[6];
  const float* w_hh     = (const float*)d_in[7];
  const float* b_ih     = (const float*)d_in[8];
  const float* b_hh     = (const float*)d_in[9];
  const float* gate_w   = (const float*)d_in[10];
  const float* gate_b   = (const float*)d_in[11];
  const float* out_w    = (const float*)d_in[12];
  const float* out_b    = (const float*)d_in[13];
  float* out = (float*)d_out;

  const int n_nodes  = in_sizes[0] / ANNOT;
  const int E        = in_sizes[1] / 2;
  const int n_graphs = out_size / 2;
  const int* src  = edge;
  const int* dstv = edge + E;

  size_t off = 0;
  auto alloc = [&](size_t bytes) { size_t o = off; off = (off + bytes + 255) & ~(size_t)255; return o; };
  char* w = (char*)d_ws;
  const int NB = (n_nodes + 1023) / 1024;

  unsigned short* h    = (unsigned short*)(w + alloc((size_t)n_nodes * HID * 2));
  unsigned short* aggr = (unsigned short*)(w + alloc((size_t)n_nodes * HID * 2));
  int*   csr_src = (int*)(w + alloc((size_t)E * 4));
  int*   row_ptr = (int*)(w + alloc((size_t)(n_nodes + 1) * 4));
  int*   cursor  = (int*)(w + alloc((size_t)n_nodes * 4));
  int*   cnt     = (int*)(w + alloc((size_t)n_nodes * 4));
  int*   bsum    = (int*)(w + alloc((size_t)NB * 4));
  int*   boff    = (int*)(w + alloc((size_t)NB * 4));
  unsigned short* Bpack = (unsigned short*)(w + alloc((size_t)NSTEPS * 8 * 8 * 64 * 8 * 2));
  float* gl      = (float*)(w + alloc((size_t)n_nodes * 4));
  float* f2      = (float*)(w + alloc((size_t)n_nodes * 2 * 4));
  unsigned* gmax = (unsigned*)(w + alloc(256));
  float* acc3    = (float*)(w + alloc(192 * 4));
  (void)ws_size; (void)n_in;

  hipMemsetAsync(cnt, 0, (size_t)n_nodes * 4, stream);
  hipMemsetAsync(gmax, 0, 256, stream);
  hipMemsetAsync(acc3, 0, 192 * 4, stream);

  const int gN64  = (n_nodes + 63) / 64;
  const int gE256 = (E + 255) / 256;
  const int gN256 = (n_nodes + 255) / 256;

  k_reduce<<<gN64, 256, 0, stream>>>(x, reduce_w, reduce_b, h, n_nodes);
  k_bbig<<<dim3(8, 8, NSTEPS), 64, 0, stream>>>(ggc_w, w_ih, w_hh, Bpack);
  k_hist<<<gE256, 256, 0, stream>>>(dstv, E, cnt);
  k_scan1<<<NB, 1024, 0, stream>>>(cnt, n_nodes, bsum);
  k_scan2<<<1, 1, 0, stream>>>(bsum, NB, boff, row_ptr, n_nodes);
  k_scan3<<<NB, 1024, 0, stream>>>(cnt, n_nodes, boff, row_ptr, cursor);
  k_fill<<<gE256, 256, 0, stream>>>(src, dstv, E, cursor, csr_src);

  for (int s = 0; s < NSTEPS; ++s) {
    k_aggr<<<(n_nodes + 3) / 4, 256, 0, stream>>>((const ushort4*)h, row_ptr, csr_src, (ushort4*)aggr, n_nodes);
    k_gru<<<(n_nodes + 127) / 128, 256, 0, stream>>>(aggr, h, Bpack + (size_t)s * 8 * 8 * 64 * 8, b_ih, b_hh, n_nodes);
  }

  k_pool1<<<gN256, 256, 0, stream>>>(h, batch, gate_w, gate_b, out_w, out_b, gl, f2, gmax, n_nodes);
  k_pool2<<<gN256, 256, 0, stream>>>(gl, f2, batch, gmax, acc3, n_nodes);
  k_pool3<<<1, 64, 0, stream>>>(acc3, out, n_graphs);
}

// Round 4
// 785.798 us; speedup vs baseline: 2.8274x; 1.2152x over previous
//
#include <hip/hip_runtime.h>
#include <math.h>

#define HID 64
#define ANNOT 512
#define NSTEPS 8
#define PCHUNK 4096
#define CSR_CAP 10240

typedef __attribute__((ext_vector_type(8))) short short8_t;
typedef __attribute__((ext_vector_type(16))) float floatx16;

__device__ __forceinline__ float sigmoidf_(float x) { return 1.0f / (1.0f + __expf(-x)); }

__device__ __forceinline__ float bf2f(unsigned short u) {
  return __uint_as_float(((unsigned)u) << 16);
}
__device__ __forceinline__ unsigned short f2bf(float f) {
  unsigned u = __float_as_uint(f);
  unsigned r = ((u >> 16) & 1u) + 0x7fffu;
  return (unsigned short)((u + r) >> 16);
}
__device__ __forceinline__ float bflo(unsigned u) { return __uint_as_float(u << 16); }
__device__ __forceinline__ float bfhi(unsigned u) { return __uint_as_float(u & 0xffff0000u); }
__device__ __forceinline__ unsigned packbf2(float a, float b) {
  return (unsigned)f2bf(a) | ((unsigned)f2bf(b) << 16);
}

__device__ __forceinline__ unsigned enc_f(float f) {
  unsigned u = __float_as_uint(f);
  return (f < 0.f) ? ~u : (u | 0x80000000u);
}
__device__ __forceinline__ float dec_f(unsigned u) {
  return (u & 0x80000000u) ? __uint_as_float(u & 0x7FFFFFFFu) : __uint_as_float(~u);
}

// ---------------- reduce GEMM: h[n,64] = x[n,512] @ Wr[512,64] + br  (h stored bf16) ----------------
__global__ __launch_bounds__(256) void k_reduce(
    const float* __restrict__ x, const float* __restrict__ Wr,
    const float* __restrict__ br, unsigned short* __restrict__ h, int n_nodes)
{
  __shared__ float As[32][64];
  __shared__ float Bs[32][64];
  const int tid = threadIdx.x;
  const int tx = tid & 15, ty = tid >> 4;
  const int bm = blockIdx.x * 64;
  float acc[4][4] = {};
  const int mA = tid >> 2;
  const int kA = (tid & 3) * 8;
  const int kB = tid >> 3;
  const int nB = (tid & 7) * 8;
  const bool mvalid = (bm + mA) < n_nodes;
  const size_t rowA = (size_t)(bm + mA) * ANNOT;

  for (int kt = 0; kt < ANNOT; kt += 32) {
    float4 a0 = make_float4(0, 0, 0, 0), a1 = a0;
    if (mvalid) {
      a0 = *(const float4*)(x + rowA + kt + kA);
      a1 = *(const float4*)(x + rowA + kt + kA + 4);
    }
    float4 b0 = *(const float4*)(Wr + (size_t)(kt + kB) * HID + nB);
    float4 b1 = *(const float4*)(Wr + (size_t)(kt + kB) * HID + nB + 4);
    __syncthreads();
    As[kA + 0][mA] = a0.x; As[kA + 1][mA] = a0.y; As[kA + 2][mA] = a0.z; As[kA + 3][mA] = a0.w;
    As[kA + 4][mA] = a1.x; As[kA + 5][mA] = a1.y; As[kA + 6][mA] = a1.z; As[kA + 7][mA] = a1.w;
    *(float4*)&Bs[kB][nB] = b0;
    *(float4*)&Bs[kB][nB + 4] = b1;
    __syncthreads();
#pragma unroll
    for (int k = 0; k < 32; ++k) {
      float4 av = *(const float4*)&As[k][ty * 4];
      float4 bv = *(const float4*)&Bs[k][tx * 4];
      acc[0][0] += av.x * bv.x; acc[0][1] += av.x * bv.y; acc[0][2] += av.x * bv.z; acc[0][3] += av.x * bv.w;
      acc[1][0] += av.y * bv.x; acc[1][1] += av.y * bv.y; acc[1][2] += av.y * bv.z; acc[1][3] += av.y * bv.w;
      acc[2][0] += av.z * bv.x; acc[2][1] += av.z * bv.y; acc[2][2] += av.z * bv.z; acc[2][3] += av.z * bv.w;
      acc[3][0] += av.w * bv.x; acc[3][1] += av.w * bv.y; acc[3][2] += av.w * bv.z; acc[3][3] += av.w * bv.w;
    }
  }
  float4 bias = *(const float4*)(br + tx * 4);
#pragma unroll
  for (int i = 0; i < 4; ++i) {
    int row = bm + ty * 4 + i;
    if (row < n_nodes) {
      ushort4 o;
      o.x = f2bf(acc[i][0] + bias.x);
      o.y = f2bf(acc[i][1] + bias.y);
      o.z = f2bf(acc[i][2] + bias.z);
      o.w = f2bf(acc[i][3] + bias.w);
      *(ushort4*)(h + (size_t)row * HID + tx * 4) = o;
    }
  }
}

// ------------- Bpack precompute: MFMA-fragment layout, bf16 -------------
__global__ void k_bbig(const float* __restrict__ ggc_w, const float* __restrict__ w_ih,
                       const float* __restrict__ w_hh, unsigned short* __restrict__ Bpack)
{
  const int nt = blockIdx.x;   // 0..7
  const int kc = blockIdx.y;   // 0..7
  const int s  = blockIdx.z;   // 0..7
  const int l  = threadIdx.x;  // 0..63
  const int c = nt * 32 + (l & 31);
  const int sec = c >> 6, f = c & 63;
  unsigned short outv[8];
#pragma unroll
  for (int j = 0; j < 8; ++j) {
    int k = kc * 16 + (l >> 5) * 8 + j;
    float v = 0.f;
    if (k < 64) {
      if (sec < 3) {
        const float* Ws = ggc_w + ((size_t)s * 64 + k) * 64;
        const float* wr = w_ih + (size_t)(sec * 64 + f) * 64;
        float a = 0.f;
        for (int q = 0; q < 64; ++q) a += Ws[q] * wr[q];
        v = a;
      }
    } else {
      int k2 = k - 64;
      if (sec == 0)      v = w_hh[(size_t)f * 64 + k2];
      else if (sec == 1) v = w_hh[(size_t)(64 + f) * 64 + k2];
      else if (sec == 3) v = w_hh[(size_t)(128 + f) * 64 + k2];
    }
    outv[j] = f2bf(v);
  }
  unsigned short* dst = Bpack + ((((size_t)s * 8 + kc) * 8 + nt) * 64 + l) * 8;
#pragma unroll
  for (int j = 0; j < 8; ++j) dst[j] = outv[j];
}

// ---------------- CSR build via bucket counting sort ----------------
// bucket = dst >> 9 (512 nodes/bucket), nbuk = ceil(n/512) <= 256

__global__ __launch_bounds__(256) void k_pcnt(const int* __restrict__ dstv, int E,
                                              int* __restrict__ bukCnt, int nbuk)
{
  __shared__ int lh[256];
  lh[threadIdx.x] = 0;
  __syncthreads();
  for (int e = blockIdx.x * blockDim.x + threadIdx.x; e < E; e += gridDim.x * blockDim.x)
    atomicAdd(&lh[dstv[e] >> 9], 1);
  __syncthreads();
  if (threadIdx.x < nbuk) {
    int v = lh[threadIdx.x];
    if (v) atomicAdd(&bukCnt[threadIdx.x], v);
  }
}

__global__ void k_bscan(const int* __restrict__ bukCnt, int nbuk,
                        int* __restrict__ bukBase, int* __restrict__ bukCur,
                        int* __restrict__ row_ptr, int n_nodes, int E)
{
  if (threadIdx.x == 0 && blockIdx.x == 0) {
    int run = 0;
    for (int b = 0; b < nbuk; ++b) { bukBase[b] = run; bukCur[b] = run; run += bukCnt[b]; }
    bukBase[nbuk] = run;
    row_ptr[n_nodes] = E;
  }
}

// partition edges into bucket-grouped record array (LDS chunk sort -> grouped writes)
__global__ __launch_bounds__(256) void k_part(
    const int* __restrict__ srcv, const int* __restrict__ dstv, int E,
    int* __restrict__ bukCur, uint2* __restrict__ rec, int nbuk)
{
  __shared__ int lhist[256], lexcl[256], lbase[256], lcur[256];
  __shared__ uint2 lrec[PCHUNK];
  __shared__ unsigned char lbuk[PCHUNK];
  const int t = threadIdx.x;
  const int nchunk = (E + PCHUNK - 1) / PCHUNK;
  for (int c = blockIdx.x; c < nchunk; c += gridDim.x) {
    const int e0 = c * PCHUNK;
    const int cnt = min(PCHUNK, E - e0);
    lhist[t] = 0;
    __syncthreads();
    int myS[16], myD[16];
#pragma unroll
    for (int i = 0; i < 16; ++i) {
      int j = t + i * 256;
      myS[i] = -1; myD[i] = 0;
      if (j < cnt) {
        int e = e0 + j;
        myS[i] = srcv[e];
        myD[i] = dstv[e];
        atomicAdd(&lhist[myD[i] >> 9], 1);
      }
    }
    __syncthreads();
    int v = lhist[t];
    lexcl[t] = v;
    __syncthreads();
    for (int d = 1; d < 256; d <<= 1) {
      int u = (t >= d) ? lexcl[t - d] : 0;
      __syncthreads();
      lexcl[t] += u;
      __syncthreads();
    }
    int excl = lexcl[t] - v;  // exclusive prefix
    __syncthreads();
    lexcl[t] = excl;
    lcur[t] = excl;
    if (v > 0) lbase[t] = atomicAdd(&bukCur[t], v);
    __syncthreads();
#pragma unroll
    for (int i = 0; i < 16; ++i) {
      if (myS[i] >= 0) {
        int b = myD[i] >> 9;
        int p = atomicAdd(&lcur[b], 1);
        lrec[p] = make_uint2((unsigned)myS[i], (unsigned)myD[i]);
        lbuk[p] = (unsigned char)b;
      }
    }
    __syncthreads();
    for (int j = t; j < cnt; j += 256) {
      int b = lbuk[j];
      rec[(size_t)lbase[b] + (j - lexcl[b])] = lrec[j];
    }
    __syncthreads();
  }
}

// per-bucket CSR: row_ptr + csr_src (built in LDS, flushed coalesced)
__global__ __launch_bounds__(512) void k_csr(
    const uint2* __restrict__ rec, const int* __restrict__ bukBase,
    int* __restrict__ row_ptr, int* __restrict__ csr_src, int n_nodes)
{
  __shared__ int cnt[512], off[512], cur[512];
  __shared__ int outbuf[CSR_CAP];
  const int b = blockIdx.x;
  const int t = threadIdx.x;
  const int beg = bukBase[b], end = bukBase[b + 1];
  const int m = end - beg;
  const int node0 = b << 9;
  cnt[t] = 0;
  __syncthreads();
  for (int j = t; j < m; j += 512)
    atomicAdd(&cnt[rec[beg + j].y & 511], 1);
  __syncthreads();
  int v = cnt[t];
  off[t] = v;
  __syncthreads();
  for (int d = 1; d < 512; d <<= 1) {
    int u = (t >= d) ? off[t - d] : 0;
    __syncthreads();
    off[t] += u;
    __syncthreads();
  }
  int excl = off[t] - v;
  cur[t] = excl;
  int node = node0 + t;
  if (node < n_nodes) row_ptr[node] = beg + excl;
  __syncthreads();
  for (int j = t; j < m; j += 512) {
    uint2 r = rec[beg + j];
    int p = atomicAdd(&cur[(int)(r.y & 511u)], 1);
    if (p < CSR_CAP) outbuf[p] = (int)r.x;
  }
  __syncthreads();
  for (int j = t; j < m; j += 512)
    csr_src[beg + j] = (j < CSR_CAP) ? outbuf[j] : 0;
}

// ---------------- per-step: CSR gather-sum of h (bf16 rows, deep MLP) ----------------
// wave = 1 node; 8 x 8-lane groups each gather a DIFFERENT edge's 128B bf16 row (16B/lane);
// 2x unroll -> 16 independent gathers in flight. Butterfly-reduce (xor 8/16/32), store bf16.
__global__ __launch_bounds__(256) void k_aggr(
    const uint4* __restrict__ h16, const int* __restrict__ row_ptr,
    const int* __restrict__ csr_src, uint4* __restrict__ aggr16, int n_nodes)
{
  const int wid = threadIdx.x >> 6;
  const int lane = threadIdx.x & 63;
  const int grp = lane >> 3;
  const int l8 = lane & 7;
  const int n = blockIdx.x * 4 + wid;
  if (n >= n_nodes) return;
  const int beg = row_ptr[n], end = row_ptr[n + 1];
  float a0 = 0.f, a1 = 0.f, a2 = 0.f, a3 = 0.f, a4 = 0.f, a5 = 0.f, a6 = 0.f, a7 = 0.f;

  int e = beg + grp;
  for (; e + 8 < end; e += 16) {
    int s0 = csr_src[e], s1 = csr_src[e + 8];
    uint4 v0 = h16[(size_t)s0 * 8 + l8];
    uint4 v1 = h16[(size_t)s1 * 8 + l8];
    a0 += bflo(v0.x) + bflo(v1.x); a1 += bfhi(v0.x) + bfhi(v1.x);
    a2 += bflo(v0.y) + bflo(v1.y); a3 += bfhi(v0.y) + bfhi(v1.y);
    a4 += bflo(v0.z) + bflo(v1.z); a5 += bfhi(v0.z) + bfhi(v1.z);
    a6 += bflo(v0.w) + bflo(v1.w); a7 += bfhi(v0.w) + bfhi(v1.w);
  }
  if (e < end) {
    int s0 = csr_src[e];
    uint4 v0 = h16[(size_t)s0 * 8 + l8];
    a0 += bflo(v0.x); a1 += bfhi(v0.x);
    a2 += bflo(v0.y); a3 += bfhi(v0.y);
    a4 += bflo(v0.z); a5 += bfhi(v0.z);
    a6 += bflo(v0.w); a7 += bfhi(v0.w);
  }

#pragma unroll
  for (int d = 8; d <= 32; d <<= 1) {
    a0 += __shfl_xor(a0, d); a1 += __shfl_xor(a1, d);
    a2 += __shfl_xor(a2, d); a3 += __shfl_xor(a3, d);
    a4 += __shfl_xor(a4, d); a5 += __shfl_xor(a5, d);
    a6 += __shfl_xor(a6, d); a7 += __shfl_xor(a7, d);
  }

  if (lane < 8) {
    uint4 o;
    o.x = packbf2(a0, a1);
    o.y = packbf2(a2, a3);
    o.z = packbf2(a4, a5);
    o.w = packbf2(a6, a7);
    aggr16[(size_t)n * 8 + lane] = o;
  }
}

// ---------------- per-step: MFMA dual-GEMM + GRU gates (in-place bf16 h update) ----------------
__global__ __launch_bounds__(256) void k_gru(
    const unsigned short* __restrict__ aggr, unsigned short* __restrict__ h,
    const unsigned short* __restrict__ Bpack_s,
    const float* __restrict__ b_ih, const float* __restrict__ b_hh, int n_nodes)
{
  const int wave = threadIdx.x >> 6;
  const int lane = threadIdx.x & 63;
  const int hi = lane >> 5;
  const int l31 = lane & 31;
  const int rbase = blockIdx.x * 128 + wave * 32;
  const int arow = rbase + l31;
  const bool avalid = arow < n_nodes;

  floatx16 acc[8];
#pragma unroll
  for (int nt = 0; nt < 8; ++nt)
#pragma unroll
    for (int j = 0; j < 16; ++j) acc[nt][j] = 0.f;

#pragma unroll
  for (int kc = 0; kc < 8; ++kc) {
    const unsigned short* Asrc = (kc < 4) ? aggr : h;
    short8_t a = {0, 0, 0, 0, 0, 0, 0, 0};
    if (avalid)
      a = *(const short8_t*)(Asrc + (size_t)arow * HID + (kc & 3) * 16 + hi * 8);
    const short8_t* Bb = (const short8_t*)(Bpack_s + (size_t)kc * 8 * 64 * 8);
#pragma unroll
    for (int nt = 0; nt < 8; ++nt) {
      short8_t b = Bb[nt * 64 + lane];
      acc[nt] = __builtin_amdgcn_mfma_f32_32x32x16_bf16(a, b, acc[nt], 0, 0, 0);
    }
  }

  float bi[2][3], bh[2][3];
#pragma unroll
  for (int half = 0; half < 2; ++half) {
    int f = half * 32 + l31;
    bi[half][0] = b_ih[f]; bi[half][1] = b_ih[64 + f]; bi[half][2] = b_ih[128 + f];
    bh[half][0] = b_hh[f]; bh[half][1] = b_hh[64 + f]; bh[half][2] = b_hh[128 + f];
  }
#pragma unroll
  for (int reg = 0; reg < 16; ++reg) {
    int row = rbase + (reg & 3) + 8 * (reg >> 2) + 4 * hi;
    if (row < n_nodes) {
#pragma unroll
      for (int half = 0; half < 2; ++half) {
        int f = half * 32 + l31;
        float rg = sigmoidf_(acc[half][reg] + bi[half][0] + bh[half][0]);
        float zg = sigmoidf_(acc[2 + half][reg] + bi[half][1] + bh[half][1]);
        float ng = tanhf(acc[4 + half][reg] + bi[half][2] + rg * (acc[6 + half][reg] + bh[half][2]));
        size_t idx = (size_t)row * HID + f;
        float hold = bf2f(h[idx]);
        h[idx] = f2bf((1.f - zg) * ng + zg * hold);
      }
    }
  }
}

// ---------------- pooling ----------------
__global__ __launch_bounds__(256) void k_pool1(
    const unsigned short* __restrict__ h, const int* __restrict__ batch,
    const float* __restrict__ gate_w, const float* __restrict__ gate_b,
    const float* __restrict__ out_w, const float* __restrict__ out_b,
    float* __restrict__ gl, float* __restrict__ f2, unsigned* __restrict__ gmax, int n_nodes)
{
  __shared__ unsigned smax[64];
  if (threadIdx.x < 64) smax[threadIdx.x] = 0u;
  __syncthreads();
  int n = blockIdx.x * blockDim.x + threadIdx.x;
  if (n < n_nodes) {
    float g = gate_b[0], f0 = out_b[0], f1 = out_b[1];
    const ushort4* hr = (const ushort4*)(h + (size_t)n * HID);
#pragma unroll
    for (int q = 0; q < 16; ++q) {
      ushort4 v = hr[q];
      float h0 = bf2f(v.x), h1 = bf2f(v.y), h2 = bf2f(v.z), h3 = bf2f(v.w);
      int k = q * 4;
      g += h0 * gate_w[k] + h1 * gate_w[k + 1] + h2 * gate_w[k + 2] + h3 * gate_w[k + 3];
      f0 += h0 * out_w[2 * k] + h1 * out_w[2 * k + 2] + h2 * out_w[2 * k + 4] + h3 * out_w[2 * k + 6];
      f1 += h0 * out_w[2 * k + 1] + h1 * out_w[2 * k + 3] + h2 * out_w[2 * k + 5] + h3 * out_w[2 * k + 7];
    }
    gl[n] = g;
    f2[2 * n] = f0;
    f2[2 * n + 1] = f1;
    atomicMax(&smax[batch[n]], enc_f(g));
  }
  __syncthreads();
  if (threadIdx.x < 64 && smax[threadIdx.x] != 0u)
    atomicMax(&gmax[threadIdx.x], smax[threadIdx.x]);
}

__global__ __launch_bounds__(256) void k_pool2(
    const float* __restrict__ gl, const float* __restrict__ f2,
    const int* __restrict__ batch, const unsigned* __restrict__ gmax,
    float* __restrict__ acc3, int n_nodes)
{
  __shared__ float sacc[192];
  int t = threadIdx.x;
  if (t < 192) sacc[t] = 0.f;
  __syncthreads();
  int n = blockIdx.x * blockDim.x + t;
  if (n < n_nodes) {
    int b = batch[n];
    float e = expf(gl[n] - dec_f(gmax[b]));
    atomicAdd(&sacc[3 * b + 0], e);
    atomicAdd(&sacc[3 * b + 1], e * f2[2 * n]);
    atomicAdd(&sacc[3 * b + 2], e * f2[2 * n + 1]);
  }
  __syncthreads();
  if (t < 192) {
    float v = sacc[t];
    if (v != 0.f) atomicAdd(&acc3[t], v);
  }
}

__global__ void k_pool3(const float* __restrict__ acc3, float* __restrict__ out, int n_graphs) {
  int g = blockIdx.x * blockDim.x + threadIdx.x;
  if (g < n_graphs) {
    float s = acc3[3 * g] + 1e-16f;
    float p0 = acc3[3 * g + 1] / s, p1 = acc3[3 * g + 2] / s;
    float m = fmaxf(p0, p1);
    float e0 = expf(p0 - m), e1 = expf(p1 - m);
    float d = e0 + e1;
    out[2 * g] = e0 / d;
    out[2 * g + 1] = e1 / d;
  }
}

// ---------------- host ----------------
extern "C" void kernel_launch(void* const* d_in, const int* in_sizes, int n_in,
                              void* d_out, int out_size, void* d_ws, size_t ws_size,
                              hipStream_t stream)
{
  const float* x        = (const float*)d_in[0];
  const int*   edge     = (const int*)d_in[1];
  const int*   batch    = (const int*)d_in[2];
  const float* reduce_w = (const float*)d_in[3];
  const float* reduce_b = (const float*)d_in[4];
  const float* ggc_w    = (const float*)d_in[5];
  const float* w_ih     = (const float*)d_in[6];
  const float* w_hh     = (const float*)d_in[7];
  const float* b_ih     = (const float*)d_in[8];
  const float* b_hh     = (const float*)d_in[9];
  const float* gate_w   = (const float*)d_in[10];
  const float* gate_b   = (const float*)d_in[11];
  const float* out_w    = (const float*)d_in[12];
  const float* out_b    = (const float*)d_in[13];
  float* out = (float*)d_out;

  const int n_nodes  = in_sizes[0] / ANNOT;
  const int E        = in_sizes[1] / 2;
  const int n_graphs = out_size / 2;
  const int* src  = edge;
  const int* dstv = edge + E;
  const int nbuk = (n_nodes + 511) >> 9;

  size_t off = 0;
  auto alloc = [&](size_t bytes) { size_t o = off; off = (off + bytes + 255) & ~(size_t)255; return o; };
  char* w = (char*)d_ws;

  unsigned short* h    = (unsigned short*)(w + alloc((size_t)n_nodes * HID * 2));
  unsigned short* aggr = (unsigned short*)(w + alloc((size_t)n_nodes * HID * 2));
  int*   csr_src = (int*)(w + alloc((size_t)E * 4));
  int*   row_ptr = (int*)(w + alloc((size_t)(n_nodes + 1) * 4));
  uint2* rec     = (uint2*)(w + alloc((size_t)E * 8));
  int*   bukCnt  = (int*)(w + alloc((size_t)(nbuk + 1) * 4));
  int*   bukBase = (int*)(w + alloc((size_t)(nbuk + 1) * 4));
  int*   bukCur  = (int*)(w + alloc((size_t)(nbuk + 1) * 4));
  unsigned short* Bpack = (unsigned short*)(w + alloc((size_t)NSTEPS * 8 * 8 * 64 * 8 * 2));
  float* gl      = (float*)(w + alloc((size_t)n_nodes * 4));
  float* f2      = (float*)(w + alloc((size_t)n_nodes * 2 * 4));
  unsigned* gmax = (unsigned*)(w + alloc(256));
  float* acc3    = (float*)(w + alloc(192 * 4));
  (void)ws_size; (void)n_in;

  hipMemsetAsync(bukCnt, 0, (size_t)(nbuk + 1) * 4, stream);
  hipMemsetAsync(gmax, 0, 256, stream);
  hipMemsetAsync(acc3, 0, 192 * 4, stream);

  const int gN64  = (n_nodes + 63) / 64;
  const int gN256 = (n_nodes + 255) / 256;
  const int nchunk = (E + PCHUNK - 1) / PCHUNK;

  k_reduce<<<gN64, 256, 0, stream>>>(x, reduce_w, reduce_b, h, n_nodes);
  k_bbig<<<dim3(8, 8, NSTEPS), 64, 0, stream>>>(ggc_w, w_ih, w_hh, Bpack);

  // CSR build (bucket counting sort)
  k_pcnt<<<1024, 256, 0, stream>>>(dstv, E, bukCnt, nbuk);
  k_bscan<<<1, 1, 0, stream>>>(bukCnt, nbuk, bukBase, bukCur, row_ptr, n_nodes, E);
  k_part<<<nchunk, 256, 0, stream>>>(src, dstv, E, bukCur, rec, nbuk);
  k_csr<<<nbuk, 512, 0, stream>>>(rec, bukBase, row_ptr, csr_src, n_nodes);

  for (int s = 0; s < NSTEPS; ++s) {
    k_aggr<<<(n_nodes + 3) / 4, 256, 0, stream>>>((const uint4*)h, row_ptr, csr_src, (uint4*)aggr, n_nodes);
    k_gru<<<(n_nodes + 127) / 128, 256, 0, stream>>>(aggr, h, Bpack + (size_t)s * 8 * 8 * 64 * 8, b_ih, b_hh, n_nodes);
  }

  k_pool1<<<gN256, 256, 0, stream>>>(h, batch, gate_w, gate_b, out_w, out_b, gl, f2, gmax, n_nodes);
  k_pool2<<<gN256, 256, 0, stream>>>(gl, f2, batch, gmax, acc3, n_nodes);
  k_pool3<<<1, 64, 0, stream>>>(acc3, out, n_graphs);
}